// Round 6
// baseline (210.295 us; speedup 1.0000x reference)
//
#include <hip/hip_runtime.h>
#include <hip/hip_fp16.h>

#define N_NODES 100000
#define N_EDGES 3200000
#define NUM_FEATURES 128
#define DIM 10
#define NUM_GRAPHS 64

#define BSHIFT 8                             // 256 nodes per bucket
#define BSIZE (1 << BSHIFT)
#define NB ((N_NODES + BSIZE - 1) / BSIZE)   // 391 buckets
#define PCHUNKS 4                            // pass2 chunks per bucket
#define EPB 5000                             // edges per placement block
#define PLACE_BLOCKS 640                     // 640 * 5000 = 3.2M exact
#define NQUAD 25000                          // 100k nodes / 4 per 32-lane group
#define GEMM_BLOCKS 1563                     // ceil(25000*32 / 512)
#define BOUND_BLOCKS 196                     // ceil(100000 / 512)
#define CAPB 16384                           // per-bucket pk region capacity
                                             // padded fill ~12.3k +- 150 -> +27 sigma
#define SCAP 9728                            // real edges per bucket cap (+17 sigma)
#define NCHUNK2 (NB * PCHUNKS)               // 1564
#define ACC_STRIDE 11
#define PAD_NODE N_NODES                     // zero row index for null edges
#define NULLPK (((BSIZE - 1) << 17) | PAD_NODE)

// f32 add of DPP row-rotated value (VALU pipe)
#define DPP_ROR_ADD(v, n)                                                        \
    (v) += __int_as_float(__builtin_amdgcn_update_dpp(                           \
        0, __float_as_int(v), 0x120 | (n), 0xF, 0xF, false))

// ---------------------------------------------------------------------------
// Fused front-end. Grid = PLACE_BLOCKS + GEMM_BLOCKS, 512 threads.
//   blocks [0, 640):    edge placement. Reservations rounded up to 16 entries
//                       (one 64B line) and pad filled with NULLPK -> every pk
//                       line fully written (no partial-line HBM write-amp,
//                       R4's penalty), enabling 2.5x placement parallelism.
//   blocks [640, 2203): h1 = feat @ W1 (dwordx4 W1 loads + 4 nodes/thread,
//                       R5's TA fix) + graph bounds + zero pad rows.
// R3 lesson: no cross-block fences/fusion (device fences = per-XCD L2
// writeback+invalidate, 3x regression).
// ---------------------------------------------------------------------------
__global__ __launch_bounds__(512) void k_front(const float* __restrict__ feat,
                                               const float* __restrict__ W1,
                                               __half* __restrict__ h1,
                                               __half* __restrict__ r,
                                               const int* __restrict__ gids,
                                               int* __restrict__ bound,
                                               const int* __restrict__ src,
                                               const int* __restrict__ dst,
                                               int* __restrict__ cnt,
                                               int* __restrict__ pk) {
    __shared__ int hd[NB];      // phase1: histogram; phase2+: absolute range end
    __shared__ int cb[NB];      // absolute write cursor

    if (blockIdx.x < PLACE_BLOCKS) {
        int base0 = blockIdx.x * EPB;
        for (int t = threadIdx.x; t < NB; t += 512) hd[t] = 0;
        __syncthreads();

        // phase 1: histogram (coalesced 4-batched dst loads)
        {
            int i = threadIdx.x;
            for (; i + 1536 < EPB; i += 2048) {
                int d0 = dst[base0 + i],        d1 = dst[base0 + i + 512];
                int d2 = dst[base0 + i + 1024], d3 = dst[base0 + i + 1536];
                atomicAdd(&hd[d0 >> BSHIFT], 1);
                atomicAdd(&hd[d1 >> BSHIFT], 1);
                atomicAdd(&hd[d2 >> BSHIFT], 1);
                atomicAdd(&hd[d3 >> BSHIFT], 1);
            }
            for (; i < EPB; i += 512)
                atomicAdd(&hd[dst[base0 + i] >> BSHIFT], 1);
        }
        __syncthreads();

        // phase 2: reserve line-aligned range; hd becomes absolute end
        for (int t = threadIdx.x; t < NB; t += 512) {
            int c = hd[t];
            if (c) {
                int cpad = (c + 15) & ~15;
                int o = atomicAdd(&cnt[t], cpad);
                cb[t] = t * CAPB + o;
                hd[t] = min(t * CAPB + o + cpad, (t + 1) * CAPB);
            } else {
                cb[t] = 0;
                hd[t] = 0;
            }
        }
        __syncthreads();

        // phase 3: place (dst L2-hot re-read; 1 LDS atomic/edge; clamp = safety)
        {
            int i = threadIdx.x;
            for (; i + 1536 < EPB; i += 2048) {
                int d0 = dst[base0 + i],        d1 = dst[base0 + i + 512];
                int d2 = dst[base0 + i + 1024], d3 = dst[base0 + i + 1536];
                int s0 = src[base0 + i],        s1 = src[base0 + i + 512];
                int s2 = src[base0 + i + 1024], s3 = src[base0 + i + 1536];
                int q0 = atomicAdd(&cb[d0 >> BSHIFT], 1);
                int q1 = atomicAdd(&cb[d1 >> BSHIFT], 1);
                int q2 = atomicAdd(&cb[d2 >> BSHIFT], 1);
                int q3 = atomicAdd(&cb[d3 >> BSHIFT], 1);
                if (q0 < ((d0 >> BSHIFT) + 1) * CAPB) pk[q0] = ((d0 & (BSIZE - 1)) << 17) | s0;
                if (q1 < ((d1 >> BSHIFT) + 1) * CAPB) pk[q1] = ((d1 & (BSIZE - 1)) << 17) | s1;
                if (q2 < ((d2 >> BSHIFT) + 1) * CAPB) pk[q2] = ((d2 & (BSIZE - 1)) << 17) | s2;
                if (q3 < ((d3 >> BSHIFT) + 1) * CAPB) pk[q3] = ((d3 & (BSIZE - 1)) << 17) | s3;
            }
            for (; i < EPB; i += 512) {
                int d = dst[base0 + i];
                int s = src[base0 + i];
                int q = atomicAdd(&cb[d >> BSHIFT], 1);
                if (q < ((d >> BSHIFT) + 1) * CAPB) pk[q] = ((d & (BSIZE - 1)) << 17) | s;
            }
        }
        __syncthreads();

        // phase 4: fill reservation pads with null edges (lines already dirty)
        for (int t = threadIdx.x; t < NB; t += 512)
            for (int q = cb[t]; q < hd[t]; ++q) pk[q] = NULLPK;
        return;
    }

    // ---- GEMM half: 4 nodes per 32-lane group ----
    int bb = blockIdx.x - PLACE_BLOCKS;

    // zero pad rows (h1[100000], r[100000]) read by null edges downstream
    if (bb == 0 && threadIdx.x == 0) {
        __half2 z = __floats2half2_rn(0.f, 0.f);
        __half2* oh = (__half2*)h1;
        __half2* orr = (__half2*)r;
#pragma unroll
        for (int j = 0; j < 5; ++j) {
            oh[(size_t)PAD_NODE * 5 + j]  = z;
            orr[(size_t)PAD_NODE * 5 + j] = z;
        }
    }

    // fused graph-boundary computation (gids sorted)
    int nb2 = bb * 512 + threadIdx.x;
    if (bb < BOUND_BLOCKS && nb2 < N_NODES) {
        int g  = gids[nb2];
        int gp = nb2 ? gids[nb2 - 1] : -1;
        for (int v = gp + 1; v <= g; ++v) bound[v] = nb2;
        if (nb2 == N_NODES - 1)
            for (int v = g + 1; v <= NUM_GRAPHS; ++v) bound[v] = N_NODES;
    }

    int gid  = bb * 512 + threadIdx.x;
    int quad = gid >> 5;                 // node quad id
    int lane = gid & 31;
    if (quad >= NQUAD) return;

    // lane's W1 slice (rows lane*4..lane*4+3, 160B contiguous) as 10 dwordx4
    float wf[40];
    {
        const float4* W14 = reinterpret_cast<const float4*>(W1 + lane * 40);
#pragma unroll
        for (int m = 0; m < 10; ++m) {
            float4 q = W14[m];
            wf[4 * m]     = q.x;
            wf[4 * m + 1] = q.y;
            wf[4 * m + 2] = q.z;
            wf[4 * m + 3] = q.w;
        }
    }

    int nbase = quad * 4;
    float4 f[4];
#pragma unroll
    for (int n = 0; n < 4; ++n)
        f[n] = *reinterpret_cast<const float4*>(feat + (size_t)(nbase + n) * NUM_FEATURES + lane * 4);

    float acc[4][DIM];
#pragma unroll
    for (int n = 0; n < 4; ++n)
#pragma unroll
        for (int k = 0; k < DIM; ++k) acc[n][k] = 0.f;

#pragma unroll
    for (int n = 0; n < 4; ++n) {
        float fv[4] = {f[n].x, f[n].y, f[n].z, f[n].w};
#pragma unroll
        for (int j = 0; j < 4; ++j)
#pragma unroll
            for (int k = 0; k < DIM; ++k)
                acc[n][k] += fv[j] * wf[j * DIM + k];
    }

    // reduce over 32 lanes: 4 in-row DPP rotate-adds (VALU) + 1 shfl_xor(16)
#pragma unroll
    for (int n = 0; n < 4; ++n)
#pragma unroll
        for (int k = 0; k < DIM; ++k) {
            float v = acc[n][k];
            DPP_ROR_ADD(v, 1);
            DPP_ROR_ADD(v, 2);
            DPP_ROR_ADD(v, 4);
            DPP_ROR_ADD(v, 8);
            acc[n][k] = v + __shfl_xor(v, 16);
        }

    if (lane == 0) {
        __half2* o = (__half2*)h1;
#pragma unroll
        for (int n = 0; n < 4; ++n)
#pragma unroll
            for (int j = 0; j < 5; ++j)
                o[(size_t)(nbase + n) * 5 + j] =
                    __floats2half2_rn(acc[n][2 * j], acc[n][2 * j + 1]);
    }
}

// ---------------------------------------------------------------------------
// Pass 1 SpMM, one block per bucket (CHUNKS=1). In-block counting sort of
// REAL edges into srt (nulls skipped; pk read twice, 2nd L2-hot), then
// exclusive-owner segmented gather (12 slots x 5 lanes, 8-deep), register
// acc, fused relu, direct fp16 write to r. part buffer + merge kernel gone.
// ---------------------------------------------------------------------------
__global__ __launch_bounds__(512) void k_spmm1(const __half* __restrict__ h,
                                               const int* __restrict__ cnt,
                                               const int* __restrict__ pk,
                                               __half* __restrict__ r) {
    __shared__ int srt[SCAP];
    __shared__ int hist[BSIZE];
    __shared__ int cur[BSIZE];

    int b   = blockIdx.x;
    int s0  = b * CAPB;
    int len = min(cnt[b], CAPB);

    for (int t = threadIdx.x; t < BSIZE; t += 512) hist[t] = 0;
    __syncthreads();

    // histogram of real edges
    {
        int i = threadIdx.x;
        for (; i + 1536 < len; i += 2048) {
            int p0 = pk[s0 + i],        p1 = pk[s0 + i + 512];
            int p2 = pk[s0 + i + 1024], p3 = pk[s0 + i + 1536];
            if ((p0 & 0x1FFFF) < N_NODES) atomicAdd(&hist[p0 >> 17], 1);
            if ((p1 & 0x1FFFF) < N_NODES) atomicAdd(&hist[p1 >> 17], 1);
            if ((p2 & 0x1FFFF) < N_NODES) atomicAdd(&hist[p2 >> 17], 1);
            if ((p3 & 0x1FFFF) < N_NODES) atomicAdd(&hist[p3 >> 17], 1);
        }
        for (; i < len; i += 512) {
            int p = pk[s0 + i];
            if ((p & 0x1FFFF) < N_NODES) atomicAdd(&hist[p >> 17], 1);
        }
    }
    __syncthreads();

    // exclusive scan of 256 bins (64-lane wave)
    if (threadIdx.x < 64) {
        int l = threadIdx.x;
        int carry = 0;
#pragma unroll
        for (int j = 0; j < 4; ++j) {
            int x = hist[j * 64 + l];
            int v = x;
#pragma unroll
            for (int off = 1; off < 64; off <<= 1) {
                int t2 = __shfl_up(v, off);
                if (l >= off) v += t2;
            }
            cur[j * 64 + l] = carry + v - x;
            carry += __shfl(v, 63);
        }
    }
    __syncthreads();

    // scatter real edges to sorted position (pk re-read, L2-hot)
    {
        int i = threadIdx.x;
        for (; i + 1536 < len; i += 2048) {
            int p0 = pk[s0 + i],        p1 = pk[s0 + i + 512];
            int p2 = pk[s0 + i + 1024], p3 = pk[s0 + i + 1536];
            if ((p0 & 0x1FFFF) < N_NODES) { int q = atomicAdd(&cur[p0 >> 17], 1); if (q < SCAP) srt[q] = p0; }
            if ((p1 & 0x1FFFF) < N_NODES) { int q = atomicAdd(&cur[p1 >> 17], 1); if (q < SCAP) srt[q] = p1; }
            if ((p2 & 0x1FFFF) < N_NODES) { int q = atomicAdd(&cur[p2 >> 17], 1); if (q < SCAP) srt[q] = p2; }
            if ((p3 & 0x1FFFF) < N_NODES) { int q = atomicAdd(&cur[p3 >> 17], 1); if (q < SCAP) srt[q] = p3; }
        }
        for (; i < len; i += 512) {
            int p = pk[s0 + i];
            if ((p & 0x1FFFF) < N_NODES) { int q = atomicAdd(&cur[p >> 17], 1); if (q < SCAP) srt[q] = p; }
        }
    }
    __syncthreads();

    int wave = threadIdx.x >> 6;
    int lane = threadIdx.x & 63;
    int slot = lane / 5;            // 0..12 (12 = idle lanes 60..63)
    int l    = lane - slot * 5;     // half2 index within the row
    const __half2* h2 = (const __half2*)h;
    __half2* r2 = (__half2*)r;

    if (slot < 12) {
        int g = wave * 12 + slot;   // 0..95
        for (int loc = g; loc < BSIZE; loc += 96) {
            int e0 = min(loc ? cur[loc - 1] : 0, SCAP);
            int e1 = min(cur[loc], SCAP);
            float ax0 = 0.f, ay0 = 0.f, ax1 = 0.f, ay1 = 0.f;
            float ax2 = 0.f, ay2 = 0.f, ax3 = 0.f, ay3 = 0.f;
            int e = e0;
            for (; e + 7 < e1; e += 8) {
                float2 v0 = __half22float2(h2[(size_t)(srt[e]     & 0x1FFFF) * 5 + l]);
                float2 v1 = __half22float2(h2[(size_t)(srt[e + 1] & 0x1FFFF) * 5 + l]);
                float2 v2 = __half22float2(h2[(size_t)(srt[e + 2] & 0x1FFFF) * 5 + l]);
                float2 v3 = __half22float2(h2[(size_t)(srt[e + 3] & 0x1FFFF) * 5 + l]);
                float2 v4 = __half22float2(h2[(size_t)(srt[e + 4] & 0x1FFFF) * 5 + l]);
                float2 v5 = __half22float2(h2[(size_t)(srt[e + 5] & 0x1FFFF) * 5 + l]);
                float2 v6 = __half22float2(h2[(size_t)(srt[e + 6] & 0x1FFFF) * 5 + l]);
                float2 v7 = __half22float2(h2[(size_t)(srt[e + 7] & 0x1FFFF) * 5 + l]);
                ax0 += v0.x + v4.x; ay0 += v0.y + v4.y;
                ax1 += v1.x + v5.x; ay1 += v1.y + v5.y;
                ax2 += v2.x + v6.x; ay2 += v2.y + v6.y;
                ax3 += v3.x + v7.x; ay3 += v3.y + v7.y;
            }
            for (; e < e1; ++e) {
                float2 v = __half22float2(h2[(size_t)(srt[e] & 0x1FFFF) * 5 + l]);
                ax0 += v.x; ay0 += v.y;
            }
            int node = (b << BSHIFT) + loc;
            if (node < N_NODES)
                r2[(size_t)node * 5 + l] =
                    __floats2half2_rn(fmaxf((ax0 + ax1) + (ax2 + ax3), 0.f),
                                      fmaxf((ay0 + ay1) + (ay2 + ay3), 0.f));
        }
    }
}

// ---------------------------------------------------------------------------
// Pass 2: bucket spans <=1 graph boundary in ~all cases. Branchless dual
// accumulator, 8-deep batched pk->r loads, global-atomic flush. Null edges
// read r[100000] = 0 -> exact zero contribution.
// ---------------------------------------------------------------------------
__global__ __launch_bounds__(512) void k_pass2(const __half* __restrict__ r,
                                               const int* __restrict__ cnt,
                                               const int* __restrict__ pk,
                                               const int* __restrict__ bound,
                                               float* __restrict__ sums) {
    __shared__ float acc[NUM_GRAPHS * ACC_STRIDE];

    int b     = blockIdx.x / PCHUNKS;
    int chunk = blockIdx.x % PCHUNKS;
    int nbase = b << BSHIFT;
    int nlast = min(nbase + BSIZE - 1, N_NODES - 1);

    int glo = 0, ghx = NUM_GRAPHS - 1;
#pragma unroll
    for (int it = 0; it < 6; ++it) {
        int mid = (glo + ghx + 1) >> 1;
        if (bound[mid] <= nbase) glo = mid; else ghx = mid - 1;
    }
    int lo2 = 0, hi2 = NUM_GRAPHS - 1;
#pragma unroll
    for (int it = 0; it < 6; ++it) {
        int mid = (lo2 + hi2 + 1) >> 1;
        if (bound[mid] <= nlast) lo2 = mid; else hi2 = mid - 1;
    }
    int ghi  = lo2;
    int span = ghi - glo;

    for (int t = threadIdx.x; t < (span + 1) * DIM; t += 512)
        acc[(glo + t / DIM) * ACC_STRIDE + t % DIM] = 0.f;
    __syncthreads();

    int s0  = b * CAPB;
    int len = min(cnt[b], CAPB);
    int c0  = s0 + (len * chunk) / PCHUNKS;
    int c1  = s0 + (len * (chunk + 1)) / PCHUNKS;

    int wave = threadIdx.x >> 6;
    int lane = threadIdx.x & 63;
    int slot = lane / 5;
    int l    = lane - slot * 5;
    const __half2* r2 = (const __half2*)r;

    if (slot < 12) {
        const int STR = 96;
        int q = wave * 12 + slot;
        int e = c0 + q;
        if (span <= 1) {
            int gA  = glo;
            int gB  = (span == 1) ? glo + 1 : glo;
            int cut = (span == 1) ? (bound[glo + 1] - nbase) : BSIZE;
            float axA = 0.f, ayA = 0.f, axB = 0.f, ayB = 0.f;
            for (; e + 7 * STR < c1; e += 8 * STR) {
                int p[8];
#pragma unroll
                for (int u = 0; u < 8; ++u) p[u] = pk[e + u * STR];
                float2 v[8];
#pragma unroll
                for (int u = 0; u < 8; ++u)
                    v[u] = __half22float2(r2[(size_t)(p[u] & 0x1FFFF) * 5 + l]);
#pragma unroll
                for (int u = 0; u < 8; ++u) {
                    bool a = (p[u] >> 17) < cut;
                    axA += a ? v[u].x : 0.f;  ayA += a ? v[u].y : 0.f;
                    axB += a ? 0.f : v[u].x;  ayB += a ? 0.f : v[u].y;
                }
            }
            for (; e < c1; e += STR) {
                int p = pk[e];
                float2 v = __half22float2(r2[(size_t)(p & 0x1FFFF) * 5 + l]);
                bool a = (p >> 17) < cut;
                axA += a ? v.x : 0.f;  ayA += a ? v.y : 0.f;
                axB += a ? 0.f : v.x;  ayB += a ? 0.f : v.y;
            }
            atomicAdd(&acc[gA * ACC_STRIDE + 2 * l], axA);
            atomicAdd(&acc[gA * ACC_STRIDE + 2 * l + 1], ayA);
            if (span == 1) {
                atomicAdd(&acc[gB * ACC_STRIDE + 2 * l], axB);
                atomicAdd(&acc[gB * ACC_STRIDE + 2 * l + 1], ayB);
            }
        } else {
            for (; e < c1; e += STR) {
                int p   = pk[e];
                int loc = p >> 17;
                float2 v = __half22float2(r2[(size_t)(p & 0x1FFFF) * 5 + l]);
                int g = glo;
                for (int gg = glo + 1; gg <= ghi; ++gg)
                    g += (loc >= bound[gg] - nbase) ? 1 : 0;
                atomicAdd(&acc[g * ACC_STRIDE + 2 * l], v.x);
                atomicAdd(&acc[g * ACC_STRIDE + 2 * l + 1], v.y);
            }
        }
    }
    __syncthreads();

    for (int t = threadIdx.x; t < (span + 1) * DIM; t += 512) {
        int g = glo + t / DIM;
        float v = acc[g * ACC_STRIDE + t % DIM];
        if (v != 0.f) atomicAdd(&sums[g * DIM + t % DIM], v);
    }
}

// out[g] = sigmoid(((sums[g]/max(cnt,1)) @ W2) @ W3)
__global__ void k_final(const float* __restrict__ sums, const int* __restrict__ bound,
                        const float* __restrict__ W2, const float* __restrict__ W3,
                        float* __restrict__ out) {
    int g = threadIdx.x;
    if (g >= NUM_GRAPHS) return;
    float c = fmaxf((float)(bound[g + 1] - bound[g]), 1.f);
    float p[DIM];
#pragma unroll
    for (int k = 0; k < DIM; ++k) p[k] = sums[g * DIM + k] / c;
    float z = 0.f;
#pragma unroll
    for (int j = 0; j < DIM; ++j) {
        float t = 0.f;
#pragma unroll
        for (int k = 0; k < DIM; ++k) t += p[k] * W2[k * DIM + j];
        z += t * W3[j];
    }
    out[g] = 1.f / (1.f + expf(-z));
}

// ---------------------------------------------------------------------------
// Workspace (bytes):
//   h1     [0,         2000128)    100001 x 10 fp16 (row 100000 = zero pad)
//   pk     [2000128,  27624704)    391 buckets x 16384 slots x 4B
//   r      [27624704, 29624832)    100001 x 10 fp16 (row 100000 = zero pad)
//   cnt    [29624832, 29626396)    391 int   \  zeroed by one 4128B memset
//   sums   [29626400, 29628960)    640 f32   /
//   bound  [29628960, 29629220)    65 int
// ---------------------------------------------------------------------------
extern "C" void kernel_launch(void* const* d_in, const int* in_sizes, int n_in,
                              void* d_out, int out_size, void* d_ws, size_t ws_size,
                              hipStream_t stream) {
    const float* feat = (const float*)d_in[0];
    const float* W1   = (const float*)d_in[1];
    const float* W2   = (const float*)d_in[2];
    const float* W3   = (const float*)d_in[3];
    const int*   src  = (const int*)d_in[4];
    const int*   dst  = (const int*)d_in[5];
    const int*   gids = (const int*)d_in[6];
    float*       out  = (float*)d_out;

    char* ws = (char*)d_ws;
    __half* h1    = (__half*)(ws);
    int*    pk    = (int*)(ws + 2000128);
    __half* r     = (__half*)(ws + 27624704);
    int*    cnt   = (int*)(ws + 29624832);
    float*  sums  = (float*)(ws + 29626400);
    int*    bound = (int*)(ws + 29628960);

    // zero cnt (391 int) + pad + sums (640 f32) in one tiny DMA
    hipMemsetAsync(ws + 29624832, 0, 4128, stream);

    k_front<<<PLACE_BLOCKS + GEMM_BLOCKS, 512, 0, stream>>>(feat, W1, h1, r, gids, bound,
                                                            src, dst, cnt, pk);
    k_spmm1<<<NB, 512, 0, stream>>>(h1, cnt, pk, r);
    k_pass2<<<NCHUNK2, 512, 0, stream>>>(r, cnt, pk, bound, sums);

    k_final<<<1, 64, 0, stream>>>(sums, bound, W2, W3, out);
}